// Round 11
// baseline (66.727 us; speedup 1.0000x reference)
//
#include <hip/hip_runtime.h>

// CharacteristicLineEncoder: B=4096, DIM=3, L=300, S=60, P=5, E=128
// out[b,s,e] = sum_p W_lr[s,p]*relu(W_le[e,:]·x[b,:,5s+p] + b_le[e]) + b_lr[s]
//            + relu( sum_l W_gn[l]*relu(W_ge[e,:]·x[b,:,l] + b_gn ... )
//
// 512 threads = 8 waves per b; lane owns e-pair {2*lane,2*lane+1} (one wave
// covers all 128 e -> minimal broadcast-LDS work, R8 lesson). FUSED sweep
// (each x-quad ds_read ONCE feeds both branches, R10 idea) but with per-wave
// state halved: wave wq owns regions 8wq..8wq+7 (40 l = 10 quads; wave 7:
// 4 regions, 5 quads) -> 16 local + 4 global accumulators, ALL with literal
// compile-time indices in explicitly unrolled group bodies (R10 lesson:
// runtime-indexed accumulator arrays leak to scratch, rule #20). Weight
// indices from readfirstlane'd wq + constants -> s_load path (R6 lesson).
// Natural register allocation — no min-waves arg (R4/R5 spill lesson).

#define RELU(v) fmaxf((v), 0.0f)

__global__ __launch_bounds__(512) void cle_kernel(
    const float* __restrict__ x,     // [B,3,300]
    const float* __restrict__ W_le,  // [E,3]
    const float* __restrict__ b_le,  // [E]
    const float* __restrict__ W_lr,  // [300]
    const float* __restrict__ b_lr,  // [60]
    const float* __restrict__ W_ge,  // [E,3]
    const float* __restrict__ b_ge,  // [E]
    const float* __restrict__ W_gn,  // [300]
    const float* __restrict__ b_gn,  // [1]
    float* __restrict__ out)         // [B,60,128]
{
    const int tid  = threadIdx.x;
    const int lane = tid & 63;
    const int wq   = __builtin_amdgcn_readfirstlane(tid >> 6);  // wave 0..7, SGPR
    const int b    = blockIdx.x;
    const int e0   = lane << 1;      // this lane's e-pair

    __shared__ __align__(16) float4 sx4[225];  // x[b]: channel c, quad j at [c*75+j]
    __shared__ float2 sgp[8][64];              // per-wave global-branch partials

    // ---- stage x[b] (3.6 KB), coalesced float4 ----
    if (tid < 225) sx4[tid] = ((const float4*)(x + (size_t)b * 900))[tid];

    // per-lane (e-pair) weights
    const float wg00 = W_ge[e0 * 3 + 0], wg01 = W_ge[e0 * 3 + 1], wg02 = W_ge[e0 * 3 + 2];
    const float wg10 = W_ge[e0 * 3 + 3], wg11 = W_ge[e0 * 3 + 4], wg12 = W_ge[e0 * 3 + 5];
    const float bg0 = b_ge[e0], bg1 = b_ge[e0 + 1];
    const float wl00 = W_le[e0 * 3 + 0], wl01 = W_le[e0 * 3 + 1], wl02 = W_le[e0 * 3 + 2];
    const float wl10 = W_le[e0 * 3 + 3], wl11 = W_le[e0 * 3 + 4], wl12 = W_le[e0 * 3 + 5];
    const float bl0 = b_le[e0], bl1 = b_le[e0 + 1];
    const float bgn = b_gn[0];

    __syncthreads();

    // ---- fused sweep over this wave's 10 (or 5) quads ----
    float ga0 = 0.f, ga1 = 0.f;          // global, e0 (2 chains)
    float gb0 = 0.f, gb1 = 0.f;          // global, e1
    // local accumulators: 8 regions x 2 e, named, literal indices only
    float la0_0 = 0.f, la0_1 = 0.f, la0_2 = 0.f, la0_3 = 0.f;
    float la0_4 = 0.f, la0_5 = 0.f, la0_6 = 0.f, la0_7 = 0.f;
    float la1_0 = 0.f, la1_1 = 0.f, la1_2 = 0.f, la1_3 = 0.f;
    float la1_4 = 0.f, la1_5 = 0.f, la1_6 = 0.f, la1_7 = 0.f;

#define GE0(cmp) RELU(fmaf(wg02, c2.cmp, fmaf(wg01, c1.cmp, fmaf(wg00, c0.cmp, bg0))))
#define GE1(cmp) RELU(fmaf(wg12, c2.cmp, fmaf(wg11, c1.cmp, fmaf(wg10, c0.cmp, bg1))))
#define LE0(cmp) RELU(fmaf(wl02, c2.cmp, fmaf(wl01, c1.cmp, fmaf(wl00, c0.cmp, bl0))))
#define LE1(cmp) RELU(fmaf(wl12, c2.cmp, fmaf(wl11, c1.cmp, fmaf(wl10, c0.cmp, bl1))))
    // one quad = 4 l: read c0,c1,c2 ONCE, feed both branches; R0..R3 literal
#define DOQ(qi, R0, R1, R2, R3)                                                \
    {                                                                          \
        const int qq = q0 + (qi);                                              \
        const int lw = qq * 4;            /* uniform -> scalarizes */          \
        const float4 c0 = sx4[qq], c1 = sx4[75 + qq], c2 = sx4[150 + qq];      \
        ga0 = fmaf(W_gn[lw + 0], GE0(x), ga0);                                 \
        gb0 = fmaf(W_gn[lw + 0], GE1(x), gb0);                                 \
        ga1 = fmaf(W_gn[lw + 1], GE0(y), ga1);                                 \
        gb1 = fmaf(W_gn[lw + 1], GE1(y), gb1);                                 \
        ga0 = fmaf(W_gn[lw + 2], GE0(z), ga0);                                 \
        gb0 = fmaf(W_gn[lw + 2], GE1(z), gb0);                                 \
        ga1 = fmaf(W_gn[lw + 3], GE0(w), ga1);                                 \
        gb1 = fmaf(W_gn[lw + 3], GE1(w), gb1);                                 \
        la0_##R0 = fmaf(W_lr[lw + 0], LE0(x), la0_##R0);                       \
        la1_##R0 = fmaf(W_lr[lw + 0], LE1(x), la1_##R0);                       \
        la0_##R1 = fmaf(W_lr[lw + 1], LE0(y), la0_##R1);                       \
        la1_##R1 = fmaf(W_lr[lw + 1], LE1(y), la1_##R1);                       \
        la0_##R2 = fmaf(W_lr[lw + 2], LE0(z), la0_##R2);                       \
        la1_##R2 = fmaf(W_lr[lw + 2], LE1(z), la1_##R2);                       \
        la0_##R3 = fmaf(W_lr[lw + 3], LE0(w), la0_##R3);                       \
        la1_##R3 = fmaf(W_lr[lw + 3], LE1(w), la1_##R3);                       \
    }

    // group 0: regions 8wq+0..3  (l = 40wq + 0..19, quads 10wq+0..4)
    {
        const int q0 = wq * 10;
        DOQ(0, 0, 0, 0, 0)   // t 0..3
        DOQ(1, 0, 1, 1, 1)   // t 4..7
        DOQ(2, 1, 1, 2, 2)   // t 8..11
        DOQ(3, 2, 2, 2, 3)   // t 12..15
        DOQ(4, 3, 3, 3, 3)   // t 16..19
    }
    // group 1: regions 8wq+4..7  (waves 0..6 only)
    if (wq < 7) {
        const int q0 = wq * 10 + 5;
        DOQ(0, 4, 4, 4, 4)
        DOQ(1, 4, 5, 5, 5)
        DOQ(2, 5, 5, 6, 6)
        DOQ(3, 6, 6, 6, 7)
        DOQ(4, 7, 7, 7, 7)
    }

    // combine global-branch partials across the 8 waves
    sgp[wq][lane] = make_float2(ga0 + ga1, gb0 + gb1);
    __syncthreads();

    float gf0, gf1;
    {
        const float2 p0 = sgp[0][lane], p1 = sgp[1][lane];
        const float2 p2 = sgp[2][lane], p3 = sgp[3][lane];
        const float2 p4 = sgp[4][lane], p5 = sgp[5][lane];
        const float2 p6 = sgp[6][lane], p7 = sgp[7][lane];
        gf0 = RELU((((p0.x + p1.x) + (p2.x + p3.x)) + ((p4.x + p5.x) + (p6.x + p7.x))) + bgn);
        gf1 = RELU((((p0.y + p1.y) + (p2.y + p3.y)) + ((p4.y + p5.y) + (p6.y + p7.y))) + bgn);
    }

    // ---- stores: wave wq owns regions s0 = 8wq .. (8 regions; wave 7: 4) ----
    float2* ob2 = (float2*)(out + (size_t)b * (60 * 128)) + lane;   // + s*64
    const int s0 = wq * 8;                   // uniform -> b_lr scalar
    ob2[(s0 + 0) * 64] = make_float2(la0_0 + gf0 + b_lr[s0 + 0], la1_0 + gf1 + b_lr[s0 + 0]);
    ob2[(s0 + 1) * 64] = make_float2(la0_1 + gf0 + b_lr[s0 + 1], la1_1 + gf1 + b_lr[s0 + 1]);
    ob2[(s0 + 2) * 64] = make_float2(la0_2 + gf0 + b_lr[s0 + 2], la1_2 + gf1 + b_lr[s0 + 2]);
    ob2[(s0 + 3) * 64] = make_float2(la0_3 + gf0 + b_lr[s0 + 3], la1_3 + gf1 + b_lr[s0 + 3]);
    if (wq < 7) {
        ob2[(s0 + 4) * 64] = make_float2(la0_4 + gf0 + b_lr[s0 + 4], la1_4 + gf1 + b_lr[s0 + 4]);
        ob2[(s0 + 5) * 64] = make_float2(la0_5 + gf0 + b_lr[s0 + 5], la1_5 + gf1 + b_lr[s0 + 5]);
        ob2[(s0 + 6) * 64] = make_float2(la0_6 + gf0 + b_lr[s0 + 6], la1_6 + gf1 + b_lr[s0 + 6]);
        ob2[(s0 + 7) * 64] = make_float2(la0_7 + gf0 + b_lr[s0 + 7], la1_7 + gf1 + b_lr[s0 + 7]);
    }
}

extern "C" void kernel_launch(void* const* d_in, const int* in_sizes, int n_in,
                              void* d_out, int out_size, void* d_ws, size_t ws_size,
                              hipStream_t stream) {
    const float* x    = (const float*)d_in[0];
    const float* W_le = (const float*)d_in[1];
    const float* b_le = (const float*)d_in[2];
    const float* W_lr = (const float*)d_in[3];
    const float* b_lr = (const float*)d_in[4];
    const float* W_ge = (const float*)d_in[5];
    const float* b_ge = (const float*)d_in[6];
    const float* W_gn = (const float*)d_in[7];
    const float* b_gn = (const float*)d_in[8];
    float* out = (float*)d_out;

    cle_kernel<<<4096, 512, 0, stream>>>(x, W_le, b_le, W_lr, b_lr,
                                         W_ge, b_ge, W_gn, b_gn, out);
}

// Round 12
// 47.235 us; speedup vs baseline: 1.4127x; 1.4127x over previous
//
#include <hip/hip_runtime.h>

// CharacteristicLineEncoder: B=4096, DIM=3, L=300, S=60, P=5, E=128
// out[b,s,e] = sum_p W_lr[s,p]*relu(W_le[e,:]·x[b,:,5s+p] + b_le[e]) + b_lr[s]
//            + relu( sum_l W_gn[l]*relu(W_ge[e,:]·x[b,:,l] + b_ge[e]) + b_gn )
//
// R9 structure (best, 45.6us) + PACKED FP32 (v_pk_fma_f32/v_pk_max_f32):
// lane owns e-pair {2*lane,2*lane+1} held as the two halves of a v2f, so
// every hot-loop op is a packed pair op -> VALU instructions halved (R11
// counters: VALU is the largest pipe, ~37us issue time). 256 thr = 4 waves
// per b; wave wq owns L-quarter (sweep1) and region range 16wq.. (sweep2).
// Weights via wave-uniform s_load (R6 lesson); per-group NAMED accumulators,
// literal indices only (R10 lesson / rule #20); natural register allocation,
// no min-waves arg (R4/R5 spill lesson).

typedef float v2f __attribute__((ext_vector_type(2)));

#define PKFMA(a, b, c) __builtin_elementwise_fma((a), (b), (c))
#define PKRELU(a)      __builtin_elementwise_max((a), (v2f)0.0f)
#define SPLAT(s)       ((v2f)(s))

__global__ __launch_bounds__(256) void cle_kernel(
    const float* __restrict__ x,     // [B,3,300]
    const float* __restrict__ W_le,  // [E,3]
    const float* __restrict__ b_le,  // [E]
    const float* __restrict__ W_lr,  // [300]
    const float* __restrict__ b_lr,  // [60]
    const float* __restrict__ W_ge,  // [E,3]
    const float* __restrict__ b_ge,  // [E]
    const float* __restrict__ W_gn,  // [300]
    const float* __restrict__ b_gn,  // [1]
    float* __restrict__ out)         // [B,60,128]
{
    const int tid  = threadIdx.x;
    const int lane = tid & 63;
    const int wq   = __builtin_amdgcn_readfirstlane(tid >> 6);  // wave 0..3, SGPR
    const int b    = blockIdx.x;
    const int e0   = lane << 1;      // this lane's e-pair

    __shared__ __align__(16) float4 sx4[225];  // x[b]: channel c, quad j at [c*75+j]
    __shared__ v2f sgp[4][64];                 // per-wave global-branch partials

    // ---- stage x[b] (3.6 KB), coalesced float4 ----
    if (tid < 225) sx4[tid] = ((const float4*)(x + (size_t)b * 900))[tid];

    // per-lane packed (e0,e1) weights
    const v2f wg0 = {W_ge[e0 * 3 + 0], W_ge[e0 * 3 + 3]};
    const v2f wg1 = {W_ge[e0 * 3 + 1], W_ge[e0 * 3 + 4]};
    const v2f wg2 = {W_ge[e0 * 3 + 2], W_ge[e0 * 3 + 5]};
    const v2f bg  = {b_ge[e0], b_ge[e0 + 1]};
    const v2f wl0 = {W_le[e0 * 3 + 0], W_le[e0 * 3 + 3]};
    const v2f wl1 = {W_le[e0 * 3 + 1], W_le[e0 * 3 + 4]};
    const v2f wl2 = {W_le[e0 * 3 + 2], W_le[e0 * 3 + 5]};
    const v2f bl  = {b_le[e0], b_le[e0 + 1]};
    const float bgn = b_gn[0];

    __syncthreads();

#define GE(cmp) PKRELU(PKFMA(wg2, SPLAT(c2.cmp), PKFMA(wg1, SPLAT(c1.cmp), PKFMA(wg0, SPLAT(c0.cmp), bg))))
#define LE(cmp) PKRELU(PKFMA(wl2, SPLAT(c2.cmp), PKFMA(wl1, SPLAT(c1.cmp), PKFMA(wl0, SPLAT(c0.cmp), bl))))

    // ---- sweep 1: global branch over this wave's L-quarter ----
    v2f ga0 = SPLAT(0.f), ga1 = SPLAT(0.f), ga2 = SPLAT(0.f), ga3 = SPLAT(0.f);
    {
        const int qb = wq * 20;
        const int nq = (wq < 3) ? 20 : 15;   // SGPR
        for (int g = 0; g < 4; ++g) {
            if (g * 5 < nq) {                // wave-uniform guard
#pragma unroll
                for (int qi = 0; qi < 5; ++qi) {
                    const int qq = qb + g * 5 + qi;
                    const int l4 = qq * 4;   // uniform -> W_gn scalarizes
                    const float4 c0 = sx4[qq], c1 = sx4[75 + qq], c2 = sx4[150 + qq];
                    ga0 = PKFMA(SPLAT(W_gn[l4 + 0]), GE(x), ga0);
                    ga1 = PKFMA(SPLAT(W_gn[l4 + 1]), GE(y), ga1);
                    ga2 = PKFMA(SPLAT(W_gn[l4 + 2]), GE(z), ga2);
                    ga3 = PKFMA(SPLAT(W_gn[l4 + 3]), GE(w), ga3);
                }
            }
        }
    }
    sgp[wq][lane] = (ga0 + ga1) + (ga2 + ga3);
    __syncthreads();

    v2f gf;
    {
        const v2f p0 = sgp[0][lane], p1 = sgp[1][lane];
        const v2f p2 = sgp[2][lane], p3 = sgp[3][lane];
        gf = PKRELU(((p0 + p1) + (p2 + p3)) + SPLAT(bgn));
    }

    // ---- sweep 2: local branch; wave wq owns regions 16wq .. (16/16/16/12) ----
    v2f* ob2 = (v2f*)(out + (size_t)b * (60 * 128)) + lane;   // + s*64

    // one quad = 4 l: packed local accumulate into literal-named accs
#define DOQ(qi, A0, A1, A2, A3)                                                \
    {                                                                          \
        const int qq = q0 + (qi);                                              \
        const int lw = qq * 4;            /* uniform -> W_lr scalarizes */     \
        const float4 c0 = sx4[qq], c1 = sx4[75 + qq], c2 = sx4[150 + qq];      \
        A0 = PKFMA(SPLAT(W_lr[lw + 0]), LE(x), A0);                            \
        A1 = PKFMA(SPLAT(W_lr[lw + 1]), LE(y), A1);                            \
        A2 = PKFMA(SPLAT(W_lr[lw + 2]), LE(z), A2);                            \
        A3 = PKFMA(SPLAT(W_lr[lw + 3]), LE(w), A3);                            \
    }

    {
        const int ng = (wq < 3) ? 4 : 3;     // SGPR: groups of 4 regions (5 quads)
        for (int g = 0; g < 4; ++g) {
            if (g < ng) {                    // wave-uniform guard
                const int q0 = wq * 20 + g * 5;
                v2f a0 = SPLAT(0.f), a1 = SPLAT(0.f), a2 = SPLAT(0.f), a3 = SPLAT(0.f);
                // element t = 4*qi + comp (l = 80wq + 20g + t), region = t/5
                DOQ(0, a0, a0, a0, a0)   // t 0..3
                DOQ(1, a0, a1, a1, a1)   // t 4..7
                DOQ(2, a1, a1, a2, a2)   // t 8..11
                DOQ(3, a2, a2, a2, a3)   // t 12..15
                DOQ(4, a3, a3, a3, a3)   // t 16..19

                const int s0 = wq * 16 + g * 4;   // uniform -> b_lr scalar
                ob2[(s0 + 0) * 64] = a0 + gf + SPLAT(b_lr[s0 + 0]);
                ob2[(s0 + 1) * 64] = a1 + gf + SPLAT(b_lr[s0 + 1]);
                ob2[(s0 + 2) * 64] = a2 + gf + SPLAT(b_lr[s0 + 2]);
                ob2[(s0 + 3) * 64] = a3 + gf + SPLAT(b_lr[s0 + 3]);
            }
        }
    }
}

extern "C" void kernel_launch(void* const* d_in, const int* in_sizes, int n_in,
                              void* d_out, int out_size, void* d_ws, size_t ws_size,
                              hipStream_t stream) {
    const float* x    = (const float*)d_in[0];
    const float* W_le = (const float*)d_in[1];
    const float* b_le = (const float*)d_in[2];
    const float* W_lr = (const float*)d_in[3];
    const float* b_lr = (const float*)d_in[4];
    const float* W_ge = (const float*)d_in[5];
    const float* b_ge = (const float*)d_in[6];
    const float* W_gn = (const float*)d_in[7];
    const float* b_gn = (const float*)d_in[8];
    float* out = (float*)d_out;

    cle_kernel<<<4096, 256, 0, stream>>>(x, W_le, b_le, W_lr, b_lr,
                                         W_ge, b_ge, W_gn, b_gn, out);
}